// Round 11
// baseline (190.355 us; speedup 1.0000x reference)
//
#include <hip/hip_runtime.h>
#include <stdint.h>

// Problem constants
#define BB 4
#define CC 256
#define HH 96
#define WW 96
#define HP 98      // halo-padded spatial dim
#define CP 264     // k-stride per x in ush (528 B; measured near-conflict-free b128 frags)
#define XT 32      // x positions per block
#define YT 2       // y rows per block
#define XE 34      // staged x entries (32 + 2 halo)

typedef __bf16 bf16x8 __attribute__((ext_vector_type(8)));
typedef __bf16 bf16x16 __attribute__((ext_vector_type(16)));
typedef float f32x4 __attribute__((ext_vector_type(4)));
typedef float f32x16 __attribute__((ext_vector_type(16)));

__device__ __forceinline__ uint16_t f2bf(float f) {
    uint32_t u = __float_as_uint(f);
    u += 0x7FFFu + ((u >> 16) & 1u);   // round-to-nearest-even
    return (uint16_t)(u >> 16);
}

// async global->LDS: lane l loads 16 B at g + l*16 B, lands at ldsbase + l*16 B.
// g must be the PER-LANE address (uniform base + lane*8 u16).  [R4-verified]
__device__ __forceinline__ void gll16(const uint16_t* g, uint16_t* l) {
    __builtin_amdgcn_global_load_lds(
        (const __attribute__((address_space(1))) uint32_t*)g,
        (__attribute__((address_space(3))) uint32_t*)l, 16, 0, 0);
}

// ---------------------------------------------------------------------------
// Pre-kernel 0: zero only the halo strips of cenT (y=0/97 rows, x=0/97 cols).
// ---------------------------------------------------------------------------
__global__ void zero_halo(uint16_t* __restrict__ cenT) {
    int idx = blockIdx.x * 256 + threadIdx.x;          // over 1552 pos * 33 uint4
    if (idx >= 1552 * 33) return;
    int p = idx / 33, q = idx - p * 33;
    int b = p / 388, s = p - b * 388;
    int y, x;
    if (s < 98)      { y = 0;       x = s; }
    else if (s < 196){ y = 97;      x = s - 98; }
    else if (s < 292){ x = 0;       y = s - 196 + 1; }
    else             { x = 97;      y = s - 292 + 1; }
    size_t o = (((size_t)b * HP + y) * HP + x) * CP + q * 8;
    *(uint4*)(cenT + o) = make_uint4(0u, 0u, 0u, 0u);
}

// ---------------------------------------------------------------------------
// Pre-kernel 1: cen (NCHW fp32) -> cenT [b][hy 98][hx 98][264] bf16 (interior).
// ---------------------------------------------------------------------------
__global__ void transpose_cen(const float* __restrict__ cen, uint16_t* __restrict__ cenT) {
    const int y = blockIdx.x, b = blockIdx.y, ch = blockIdx.z, tid = threadIdx.x;
    __shared__ uint16_t ldsX[128 * 100];

    #pragma unroll
    for (int i = 0; i < 12; ++i) {
        int f = i * 256 + tid;            // 0..3071: 128 c x 24 xq
        int c = f / 24, xq = f % 24;
        float4 v = *(const float4*)(cen + ((((size_t)b * CC + ch * 128 + c) * HH + y) * WW + xq * 4));
        uint2 pk;
        pk.x = (uint32_t)f2bf(v.x) | ((uint32_t)f2bf(v.y) << 16);
        pk.y = (uint32_t)f2bf(v.z) | ((uint32_t)f2bf(v.w) << 16);
        *(uint2*)(&ldsX[c * 100 + xq * 4]) = pk;
    }
    __syncthreads();
    #pragma unroll
    for (int i = 0; i < 6; ++i) {
        int t = i * 256 + tid;            // 0..1535: 96 x * 16 cq
        int x = t % 96, cq = t / 96;
        uint32_t w0, w1, w2, w3;
        w0 = (uint32_t)ldsX[(cq * 8 + 0) * 100 + x] | ((uint32_t)ldsX[(cq * 8 + 1) * 100 + x] << 16);
        w1 = (uint32_t)ldsX[(cq * 8 + 2) * 100 + x] | ((uint32_t)ldsX[(cq * 8 + 3) * 100 + x] << 16);
        w2 = (uint32_t)ldsX[(cq * 8 + 4) * 100 + x] | ((uint32_t)ldsX[(cq * 8 + 5) * 100 + x] << 16);
        w3 = (uint32_t)ldsX[(cq * 8 + 6) * 100 + x] | ((uint32_t)ldsX[(cq * 8 + 7) * 100 + x] << 16);
        size_t o = (((size_t)b * HP + (y + 1)) * HP + (x + 1)) * CP + ch * 128 + cq * 8;
        *(uint4*)(cenT + o) = make_uint4(w0, w1, w2, w3);
    }
}

// ---------------------------------------------------------------------------
// Pre-kernel 2: W3 -> W3bf, LANE-LINEAR frag blocks [R4-verified]:
// for (g, t=n>>5, ks=k>>4) a 1 KiB block; lane l = kh*32+col holds its 8 bf16
// at byte offset l*16.  One gll16 (per-lane source) == one frag block; the
// ds_read_b128 back (offset lane*16 B) is conflict-free linear.
// ---------------------------------------------------------------------------
__global__ void cvt_w3(const float* __restrict__ W3, uint16_t* __restrict__ W3bf) {
    int e = (blockIdx.x * 256 + threadIdx.x) * 4;   // 0..589823
    int g = e >> 16, n = (e >> 8) & 255, k = e & 255;
    float4 v = *(const float4*)(W3 + e);
    uint2 pk;
    pk.x = (uint32_t)f2bf(v.x) | ((uint32_t)f2bf(v.y) << 16);
    pk.y = (uint32_t)f2bf(v.z) | ((uint32_t)f2bf(v.w) << 16);
    size_t o = (size_t)(((g * 8 + (n >> 5)) * 16 + (k >> 4)) * 512)
             + ((k >> 3) & 1) * 256 + (n & 31) * 8 + (k & 7);
    *(uint2*)(W3bf + o) = pk;
}

// ---------------------------------------------------------------------------
// Main kernel R11 (= R10 resubmitted; R10 bench was an infra flake):
// grid (3, 48, 4) = 576 blocks, 256 thr (4 waves).
// Block tile: 64 pos (2 rows x 32 x) x 256 ch; wave wv owns ch-tiles
// (2wv, 2wv+1).  A-operand flows global -> LDS via async DMA
// (global_load_lds) into a PER-WAVE-PRIVATE 8 KB double buffer:
//   pair P = 2 ks = 4 frag-units (2 tiles x 2 ks), 4 gll16/wave.
//   Phase p (8/g): s_waitcnt vmcnt(4)  [pair p retired, pair p+1 in flight —
//   counted, NEVER drained to 0 mid-loop] -> ds_read 4 A + 4 B -> 16 MFMA ->
//   sched_barrier -> issue pair p+2 into the buffer just freed.
// No barriers in the K-loop (each wave stages exactly what it reads), so the
// R4 vmcnt(0)-drain anti-pattern is gone; the DMA engine supplies the
// outstanding-transfer capacity that register A-queues could not (R1/R7/R8
// all pinned at ~150 cyc/MFMA/SIMD by per-wave miss tracking).
// Regs: acc 64 + fin-bf16 32 AGPR + ~80 arch (queues gone) -> 2 blocks/CU;
// LDS 35.9 + 32 + 2 = 70.7 KB -> 2 blocks/CU fits (141 KB).
// Norm: in-lane FMA + shfl_xor(32) + ping-pong ldsP -> ONE barrier per g.
// ---------------------------------------------------------------------------
__global__ __launch_bounds__(256, 2)
void ecm_main(const float* __restrict__ cen, const uint16_t* __restrict__ cenT,
              const uint16_t* __restrict__ W3bf, float* __restrict__ out) {
    const int tid = threadIdx.x;
    const int wv = tid >> 6, lane = tid & 63, col = lane & 31, kh = lane >> 5;
    const int x0 = blockIdx.x * XT, y0 = blockIdx.y * YT, b = blockIdx.z;

    __shared__ __align__(16) uint16_t ldsA[YT * XE * CP];   // 35,904 B (B operand)
    __shared__ __align__(16) uint16_t ldsW[4 * 4096];       // 32,768 B (per-wave A dbuf)
    __shared__ __align__(16) float ldsP[2][64][4];          // ping-pong norm partials

    // g processed in dy-groups; dgOrd[idx] = reference g index, dx = idx%3 - 1.
    const int dgOrd[9] = {0, 1, 2, 7, 8, 3, 6, 5, 4};

    const int fo = lane * 8;                 // lane-linear A-frag read offset (u16)
    uint16_t* wds = ldsW + wv * 4096;        // this wave's private 2x2048-u16 dbuf
    bf16x16 finA0 = {}, finA1 = {}, finB0 = {}, finB1 = {};

    #pragma unroll 1
    for (int idx = 0; idx < 9; ++idx) {
        const int g = dgOrd[idx], dg = idx / 3, dx = idx % 3 - 1;

        if (idx % 3 == 0) {
            // All waves passed the previous g's norm barrier => their ldsA reads
            // are done.  (That barrier also drained vmcnt, and the K-loop ends
            // with vmcnt(0) at phase 7 — clean slate for the staging loads.)
            for (int r = 0; r < YT; ++r) {
                const uint4* gs = (const uint4*)(cenT + (((size_t)b * HP + (y0 + dg + r)) * HP + x0) * CP);
                uint4* ls = (uint4*)(ldsA + r * XE * CP);
                for (int c = tid; c < XE * CP / 8; c += 256) ls[c] = gs[c];
            }
            __syncthreads();
        }

        const uint16_t* wsrc = W3bf + (size_t)g * 65536 + fo;   // per-lane A source
        const int a0 = (col + dx + 1) * CP + kh * 8;
        const int a1 = a0 + XE * CP;

        // prologue: issue pairs 0 and 1 (unit j: tile 2wv+(j&1), sub-ks j>>1)
        #pragma unroll
        for (int q = 0; q < 2; ++q)
            #pragma unroll
            for (int j = 0; j < 4; ++j) {
                int t = 2 * wv + (j & 1), ksa = 2 * q + (j >> 1);
                gll16(wsrc + ((size_t)t * 16 + ksa) * 512, wds + q * 2048 + j * 512);
            }

        f32x16 aA0 = {}, aA1 = {}, aB0 = {}, aB1 = {};

        #pragma unroll
        for (int p = 0; p < 8; ++p) {
            // counted wait: my pair-p DMA retired; pair p+1 stays in flight.
            if (p < 7) asm volatile("s_waitcnt vmcnt(4)" ::: "memory");
            else       asm volatile("s_waitcnt vmcnt(0)" ::: "memory");
            __builtin_amdgcn_sched_barrier(0);

            const uint16_t* wbuf = wds + (p & 1) * 2048;
            #pragma unroll
            for (int s = 0; s < 2; ++s) {
                const int ks = 2 * p + s;
                bf16x8 wa = *(const bf16x8*)(wbuf + (s * 2 + 0) * 512 + fo);
                bf16x8 wb = *(const bf16x8*)(wbuf + (s * 2 + 1) * 512 + fo);
                bf16x8 b0 = *(const bf16x8*)(ldsA + a0 + ks * 16);
                bf16x8 b1 = *(const bf16x8*)(ldsA + a1 + ks * 16);
                aA0 = __builtin_amdgcn_mfma_f32_32x32x16_bf16(wa, b0, aA0, 0, 0, 0);
                aB0 = __builtin_amdgcn_mfma_f32_32x32x16_bf16(wb, b0, aB0, 0, 0, 0);
                aA1 = __builtin_amdgcn_mfma_f32_32x32x16_bf16(wa, b1, aA1, 0, 0, 0);
                aB1 = __builtin_amdgcn_mfma_f32_32x32x16_bf16(wb, b1, aB1, 0, 0, 0);
            }

            // fence, then refill the buffer this phase just finished reading.
            __builtin_amdgcn_sched_barrier(0);
            if (p < 6) {
                #pragma unroll
                for (int j = 0; j < 4; ++j) {
                    int t = 2 * wv + (j & 1), ksa = 2 * (p + 2) + (j >> 1);
                    gll16(wsrc + ((size_t)t * 16 + ksa) * 512,
                          wds + (p & 1) * 2048 + j * 512);
                }
            }
        }

        // Per-position ||Y||^2 partial over this wave's 64 ch (both tiles).
        float s0 = 0.f, s1 = 0.f;
        #pragma unroll
        for (int r = 0; r < 16; ++r) {
            s0 += aA0[r] * aA0[r] + aB0[r] * aB0[r];
            s1 += aA1[r] * aA1[r] + aB1[r] * aB1[r];
        }
        s0 += __shfl_xor(s0, 32, 64);
        s1 += __shfl_xor(s1, 32, 64);
        if (kh == 0) { ldsP[idx & 1][col][wv] = s0; ldsP[idx & 1][32 + col][wv] = s1; }
        __syncthreads();   // the ONLY barrier per g (ping-pong covers WAR)

        f32x4 pa = *(const f32x4*)&ldsP[idx & 1][col][0];
        f32x4 qa = *(const f32x4*)&ldsP[idx & 1][32 + col][0];
        float n0 = pa[0] + pa[1] + pa[2] + pa[3];
        float n1 = qa[0] + qa[1] + qa[2] + qa[3];
        const float sgn = (g == 8) ? 1.f : -1.f;
        float sc0 = sgn / fmaxf(sqrtf(n0), 1e-12f);
        float sc1 = sgn / fmaxf(sqrtf(n1), 1e-12f);
        #pragma unroll
        for (int r = 0; r < 16; ++r) {
            finA0[r] = (__bf16)((float)finA0[r] + aA0[r] * sc0);
            finB0[r] = (__bf16)((float)finB0[r] + aB0[r] * sc0);
            finA1[r] = (__bf16)((float)finA1[r] + aA1[r] * sc1);
            finB1[r] = (__bf16)((float)finB1[r] + aB1[r] * sc1);
        }
    }

    // Epilogue: out = fin + cen. D row->ch: (reg&3) + 8*(reg>>2) + 4*kh (+64*wv / +32 tileB).
    #pragma unroll
    for (int r = 0; r < 16; ++r) {
        int chA = wv * 64 + (r & 3) + 8 * (r >> 2) + 4 * kh;
        size_t oA0 = (((size_t)b * CC + chA) * HH + y0) * WW + (x0 + col);
        size_t oA1 = oA0 + WW;
        out[oA0] = (float)finA0[r] + cen[oA0];
        out[oA1] = (float)finA1[r] + cen[oA1];
        size_t oB0 = oA0 + (size_t)32 * HH * WW;
        size_t oB1 = oB0 + WW;
        out[oB0] = (float)finB0[r] + cen[oB0];
        out[oB1] = (float)finB1[r] + cen[oB1];
    }
}

extern "C" void kernel_launch(void* const* d_in, const int* in_sizes, int n_in,
                              void* d_out, int out_size, void* d_ws, size_t ws_size,
                              hipStream_t stream) {
    const float* cen = (const float*)d_in[0];
    // d_in[1] = W1, d_in[2] = W2: dead code (softmax over size-1 axis == 1.0)
    const float* W3 = (const float*)d_in[3];
    float* out = (float*)d_out;

    uint16_t* cenT = (uint16_t*)d_ws;                         // [4][98][98][264] bf16
    const size_t cenT_elems = (size_t)BB * HP * HP * CP;
    uint16_t* W3bf = cenT + cenT_elems;                       // [9][8][16][512] bf16

    zero_halo<<<201, 256, 0, stream>>>(cenT);
    transpose_cen<<<dim3(HH, BB, 2), 256, 0, stream>>>(cen, cenT);
    cvt_w3<<<576, 256, 0, stream>>>(W3, W3bf);
    ecm_main<<<dim3(3, 48, 4), 256, 0, stream>>>(cen, cenT, W3bf, out);
}

// Round 12
// 160.829 us; speedup vs baseline: 1.1836x; 1.1836x over previous
//
#include <hip/hip_runtime.h>
#include <stdint.h>

// Problem constants
#define BB 4
#define CC 256
#define HH 96
#define WW 96
#define HP 98      // halo-padded spatial dim
#define CP 264     // k-stride per x in ush (528 B; measured near-conflict-free b128 frags)
#define XT 32      // x positions per block
#define YT 6       // y rows per block (R12: 192 blocks -> A-traffic 216 MB, single round)
#define XE 34      // staged x entries (32 + 2 halo)

typedef __bf16 bf16x8 __attribute__((ext_vector_type(8)));
typedef __bf16 bf16x16 __attribute__((ext_vector_type(16)));
typedef float f32x4 __attribute__((ext_vector_type(4)));
typedef float f32x16 __attribute__((ext_vector_type(16)));

__device__ __forceinline__ uint16_t f2bf(float f) {
    uint32_t u = __float_as_uint(f);
    u += 0x7FFFu + ((u >> 16) & 1u);   // round-to-nearest-even
    return (uint16_t)(u >> 16);
}

// ---------------------------------------------------------------------------
// Pre-kernel 0: zero only the halo strips of cenT (y=0/97 rows, x=0/97 cols).
// ---------------------------------------------------------------------------
__global__ void zero_halo(uint16_t* __restrict__ cenT) {
    int idx = blockIdx.x * 256 + threadIdx.x;          // over 1552 pos * 33 uint4
    if (idx >= 1552 * 33) return;
    int p = idx / 33, q = idx - p * 33;
    int b = p / 388, s = p - b * 388;
    int y, x;
    if (s < 98)      { y = 0;       x = s; }
    else if (s < 196){ y = 97;      x = s - 98; }
    else if (s < 292){ x = 0;       y = s - 196 + 1; }
    else             { x = 97;      y = s - 292 + 1; }
    size_t o = (((size_t)b * HP + y) * HP + x) * CP + q * 8;
    *(uint4*)(cenT + o) = make_uint4(0u, 0u, 0u, 0u);
}

// ---------------------------------------------------------------------------
// Pre-kernel 1: cen (NCHW fp32) -> cenT [b][hy 98][hx 98][264] bf16 (interior).
// ---------------------------------------------------------------------------
__global__ void transpose_cen(const float* __restrict__ cen, uint16_t* __restrict__ cenT) {
    const int y = blockIdx.x, b = blockIdx.y, ch = blockIdx.z, tid = threadIdx.x;
    __shared__ uint16_t ldsX[128 * 100];

    #pragma unroll
    for (int i = 0; i < 12; ++i) {
        int f = i * 256 + tid;            // 0..3071: 128 c x 24 xq
        int c = f / 24, xq = f % 24;
        float4 v = *(const float4*)(cen + ((((size_t)b * CC + ch * 128 + c) * HH + y) * WW + xq * 4));
        uint2 pk;
        pk.x = (uint32_t)f2bf(v.x) | ((uint32_t)f2bf(v.y) << 16);
        pk.y = (uint32_t)f2bf(v.z) | ((uint32_t)f2bf(v.w) << 16);
        *(uint2*)(&ldsX[c * 100 + xq * 4]) = pk;
    }
    __syncthreads();
    #pragma unroll
    for (int i = 0; i < 6; ++i) {
        int t = i * 256 + tid;            // 0..1535: 96 x * 16 cq
        int x = t % 96, cq = t / 96;
        uint32_t w0, w1, w2, w3;
        w0 = (uint32_t)ldsX[(cq * 8 + 0) * 100 + x] | ((uint32_t)ldsX[(cq * 8 + 1) * 100 + x] << 16);
        w1 = (uint32_t)ldsX[(cq * 8 + 2) * 100 + x] | ((uint32_t)ldsX[(cq * 8 + 3) * 100 + x] << 16);
        w2 = (uint32_t)ldsX[(cq * 8 + 4) * 100 + x] | ((uint32_t)ldsX[(cq * 8 + 5) * 100 + x] << 16);
        w3 = (uint32_t)ldsX[(cq * 8 + 6) * 100 + x] | ((uint32_t)ldsX[(cq * 8 + 7) * 100 + x] << 16);
        size_t o = (((size_t)b * HP + (y + 1)) * HP + (x + 1)) * CP + ch * 128 + cq * 8;
        *(uint4*)(cenT + o) = make_uint4(w0, w1, w2, w3);
    }
}

// ---------------------------------------------------------------------------
// Pre-kernel 2: W3 [9][256 n][256 k] fp32 -> W3bf [g][t 8][ks 16][m 32][kh 2][8]
// A-frag (32x32x16: lane m holds k = kh*8 + j) for (g,t,ks) = 1 KiB contiguous.
// (R1-proven layout; frags read direct-to-register in ecm_main.)
// ---------------------------------------------------------------------------
__global__ void cvt_w3(const float* __restrict__ W3, uint16_t* __restrict__ W3bf) {
    int e = (blockIdx.x * 256 + threadIdx.x) * 4;   // 0..589823
    int g = e >> 16, n = (e >> 8) & 255, k = e & 255;
    float4 v = *(const float4*)(W3 + e);
    uint2 pk;
    pk.x = (uint32_t)f2bf(v.x) | ((uint32_t)f2bf(v.y) << 16);
    pk.y = (uint32_t)f2bf(v.z) | ((uint32_t)f2bf(v.w) << 16);
    size_t o = (size_t)(((g * 8 + (n >> 5)) * 16 + (k >> 4)) * 512)
             + (n & 31) * 16 + ((k >> 3) & 1) * 8 + (k & 7);
    *(uint2*)(W3bf + o) = pk;
}

// ---------------------------------------------------------------------------
// Main kernel R12: grid (3 xt, 16 yt, 4 b) = 192 blocks, 512 thr (8 waves).
// Block tile: 192 positions (6 rows x 32 x) x 256 ch.
// Diagnosis (R1..R11): pace is set by CHIP-WIDE A-traffic = blocks x 1.125 MB
// (each block streams all of W3bf); occupancy/prefetch-depth/DMA all null.
// R9 (288 blocks) proved the lever (1.53x busy pace) but lost it to grid
// quantization.  R12: 192 blocks = ONE round on 256 CUs (no tail), A-traffic
// 216 MB (1/3 of R8), and all 8 halo rows staged ONCE (143.6 KB LDS) -- no
// in-loop restage, no restage barriers, cenT re-read 62 -> 28 MB.
// Wave (c2=wv&3, p3=wv>>2) owns ch-tiles {2c2,2c2+1} x rows {3p3..3p3+2}:
// per ks = 2 A-loads (L2) + 3 B-reads (LDS) + 6 MFMAs on 6 chains.
// Regs (2 waves/SIMD budget 256): acc 96 + fin-bf16 48 + A-queue depth-2 16
// + B 24 + addr ~50 = ~235.  LDS 143.6 + 6 KB = 149.8 <= 160 KB.
// Norm: in-lane FMA + shfl_xor(32) + ldsP[2][192][4] ping-pong, ONE barrier/g.
// ---------------------------------------------------------------------------
__global__ __launch_bounds__(512, 2)
void ecm_main(const float* __restrict__ cen, const uint16_t* __restrict__ cenT,
              const uint16_t* __restrict__ W3bf, float* __restrict__ out) {
    const int tid = threadIdx.x;
    const int wv = tid >> 6, lane = tid & 63, col = lane & 31, kh = lane >> 5;
    const int c2 = wv & 3, p3 = wv >> 2;           // ch-pair, row-triple
    const int x0 = blockIdx.x * XT, y0 = blockIdx.y * YT, b = blockIdx.z;

    __shared__ __align__(16) uint16_t ldsA[8 * XE * CP];    // 143,616 B (8 halo rows)
    __shared__ __align__(16) float ldsP[2][192][4];         // ping-pong norm partials (6 KB)

    // g processed in dy-groups; dgOrd[idx] = reference g index, dx = idx%3 - 1.
    const int dgOrd[9] = {0, 1, 2, 7, 8, 3, 6, 5, 4};

    // Stage ALL 8 halo rows once (cenT halo rows y0 .. y0+7). Read-only after.
    for (int rr = 0; rr < 8; ++rr) {
        const uint4* gs = (const uint4*)(cenT + (((size_t)b * HP + (y0 + rr)) * HP + x0) * CP);
        uint4* ls = (uint4*)(ldsA + rr * XE * CP);
        for (int c = tid; c < XE * CP / 8; c += 512) ls[c] = gs[c];
    }
    __syncthreads();

    // wave owns ch-tiles 2*c2 and 2*c2+1 (adjacent 16-KB A-streams per g)
    const uint16_t* wbA = W3bf + (size_t)(2 * c2) * (16 * 512) + col * 16 + kh * 8;
    bf16x16 fA[3] = {}, fB[3] = {};                // packed bf16 fin (6 x 8 regs)

    #pragma unroll 1
    for (int idx = 0; idx < 9; ++idx) {
        const int g = dgOrd[idx], dg = idx / 3, dx = idx % 3 - 1;

        const uint16_t* wgA = wbA + (size_t)g * 65536;
        const uint16_t* wgB = wgA + 16 * 512;                 // second ch-tile
        // wave's three rows: local rows 3p3+rr; LDS row = local + dg
        int a[3];
        #pragma unroll
        for (int rr = 0; rr < 3; ++rr)
            a[rr] = ((dg + 3 * p3 + rr) * XE + (col + dx + 1)) * CP + kh * 8;

        f32x16 aA[3] = {}, aB[3] = {};

        // A: depth-2 rotating queue (static ks&1); B: 1-deep next-row regs.
        bf16x8 qA[2], qB[2];
        qA[0] = *(const bf16x8*)(wgA);
        qB[0] = *(const bf16x8*)(wgB);
        qA[1] = *(const bf16x8*)(wgA + 512);
        qB[1] = *(const bf16x8*)(wgB + 512);
        bf16x8 bR[3];
        #pragma unroll
        for (int rr = 0; rr < 3; ++rr) bR[rr] = *(const bf16x8*)(ldsA + a[rr]);

        #pragma unroll
        for (int ks = 0; ks < 16; ++ks) {
            bf16x8 wa = qA[ks & 1], wb = qB[ks & 1];
            if (ks + 2 < 16) {
                qA[ks & 1] = *(const bf16x8*)(wgA + (ks + 2) * 512);
                qB[ks & 1] = *(const bf16x8*)(wgB + (ks + 2) * 512);
            }
            bf16x8 bN[3];
            #pragma unroll
            for (int rr = 0; rr < 3; ++rr)
                bN[rr] = (ks + 1 < 16) ? *(const bf16x8*)(ldsA + a[rr] + (ks + 1) * 16)
                                       : bR[rr];
            __builtin_amdgcn_s_setprio(1);
            #pragma unroll
            for (int rr = 0; rr < 3; ++rr) {
                aA[rr] = __builtin_amdgcn_mfma_f32_32x32x16_bf16(wa, bR[rr], aA[rr], 0, 0, 0);
                aB[rr] = __builtin_amdgcn_mfma_f32_32x32x16_bf16(wb, bR[rr], aB[rr], 0, 0, 0);
            }
            __builtin_amdgcn_s_setprio(0);
            #pragma unroll
            for (int rr = 0; rr < 3; ++rr) bR[rr] = bN[rr];
        }

        // Per-position ||Y||^2 partial over this wave's 64 ch (both tiles).
        float s[3];
        #pragma unroll
        for (int rr = 0; rr < 3; ++rr) {
            float t = 0.f;
            #pragma unroll
            for (int r = 0; r < 16; ++r) t += aA[rr][r] * aA[rr][r] + aB[rr][r] * aB[rr][r];
            t += __shfl_xor(t, 32, 64);
            s[rr] = t;
        }
        if (kh == 0) {
            #pragma unroll
            for (int rr = 0; rr < 3; ++rr)
                ldsP[idx & 1][(3 * p3 + rr) * 32 + col][c2] = s[rr];
        }
        __syncthreads();   // the ONLY barrier per g (ping-pong covers WAR)

        const float sgn = (g == 8) ? 1.f : -1.f;
        #pragma unroll
        for (int rr = 0; rr < 3; ++rr) {
            f32x4 pa = *(const f32x4*)&ldsP[idx & 1][(3 * p3 + rr) * 32 + col][0];
            float n = pa[0] + pa[1] + pa[2] + pa[3];
            float sc = sgn / fmaxf(sqrtf(n), 1e-12f);
            #pragma unroll
            for (int r = 0; r < 16; ++r) {
                fA[rr][r] = (__bf16)((float)fA[rr][r] + aA[rr][r] * sc);
                fB[rr][r] = (__bf16)((float)fB[rr][r] + aB[rr][r] * sc);
            }
        }
    }

    // Epilogue: out = fin + cen. D row->ch: (reg&3) + 8*(reg>>2) + 4*kh
    // (+64*c2 base, +32 for tile B); row = y0 + 3*p3 + rr.
    #pragma unroll
    for (int rr = 0; rr < 3; ++rr) {
        #pragma unroll
        for (int r = 0; r < 16; ++r) {
            int chA = c2 * 64 + (r & 3) + 8 * (r >> 2) + 4 * kh;
            size_t oA = (((size_t)b * CC + chA) * HH + (y0 + 3 * p3 + rr)) * WW + (x0 + col);
            out[oA] = (float)fA[rr][r] + cen[oA];
            size_t oB = oA + (size_t)32 * HH * WW;
            out[oB] = (float)fB[rr][r] + cen[oB];
        }
    }
}

extern "C" void kernel_launch(void* const* d_in, const int* in_sizes, int n_in,
                              void* d_out, int out_size, void* d_ws, size_t ws_size,
                              hipStream_t stream) {
    const float* cen = (const float*)d_in[0];
    // d_in[1] = W1, d_in[2] = W2: dead code (softmax over size-1 axis == 1.0)
    const float* W3 = (const float*)d_in[3];
    float* out = (float*)d_out;

    uint16_t* cenT = (uint16_t*)d_ws;                         // [4][98][98][264] bf16
    const size_t cenT_elems = (size_t)BB * HP * HP * CP;
    uint16_t* W3bf = cenT + cenT_elems;                       // [9][8][16][512] bf16

    zero_halo<<<201, 256, 0, stream>>>(cenT);
    transpose_cen<<<dim3(HH, BB, 2), 256, 0, stream>>>(cen, cenT);
    cvt_w3<<<576, 256, 0, stream>>>(W3, W3bf);
    ecm_main<<<dim3(3, 16, 4), 512, 0, stream>>>(cen, cenT, W3bf, out);
}